// Round 1
// baseline (21919.353 us; speedup 1.0000x reference)
//
#include <hip/hip_runtime.h>

// MultiAgentGRULoop: 3-layer GRU, B=4096 independent sequences, T=64, H=128.
// Round 1: correctness-first f32 baseline.
//   - 256 blocks x 384 threads; each block owns 16 batch rows for the whole
//     T x L recurrence (no inter-block sync needed; batch is independent).
//   - h state + current-layer input in LDS; weights staged per cell in
//     K-tiles of 32 with XOR-swizzled 16B chunks (key (col>>2)&7) so the
//     stride-4-row b128 weight reads spread uniformly over bank groups.
//   - Each thread: 4 rows x 4 gate-cols tile, separate Wi.in / Wh.h accums.
//   - invalid mask read as int32 (harness "integer -> const int*" convention).

#define T_STEPS 64
#define HID 128
#define NL 3
#define G3 384          // 3*HID, torch gate order r,z,n
#define RB 16           // batch rows per block
#define NTHR 384
#define KT 32           // k-tile (floats)
#define NKT 4           // 128/KT
#define NBLK 256        // NBLK*RB = 4096

__device__ __forceinline__ float sigmoid_f(float v) {
  return 1.0f / (1.0f + __expf(-v));
}
__device__ __forceinline__ float tanh_f(float v) {
  // tanh(v) = 1 - 2/(e^{2v}+1); saturates correctly at +-inf
  return 1.0f - 2.0f / (__expf(2.0f * v) + 1.0f);
}

__global__ __launch_bounds__(NTHR) void gru_f32(
    const float* __restrict__ x, const int* __restrict__ invalid,
    const float* __restrict__ w_ih, const float* __restrict__ w_hh,
    const float* __restrict__ b_ih, const float* __restrict__ b_hh,
    float* __restrict__ out)
{
  // 128 KB static LDS total -> 1 block/CU
  __shared__ float4 wi4[G3 * 8];        // 48 KB: staged Wi k-tile (gate overlay after MAC)
  __shared__ float4 wh4[G3 * 8];        // 48 KB: staged Wh k-tile (gate overlay)
  __shared__ float4 in4[RB * 32];       //  8 KB: current layer input rows [16][128]
  __shared__ float4 h4[NL * RB * 32];   // 24 KB: hidden state [3][16][128]

  const int tid = threadIdx.x;
  const int row_base = (int)blockIdx.x * RB;

  const int rg  = tid / 96;   // 0..3  -> rows 4*rg .. 4*rg+3
  const int cg  = tid % 96;   // 0..95 -> gate cols 4*cg .. 4*cg+3
  const int swz = cg & 7;     // swizzle key == (col>>2)&7 for this thread's cols

  float* gA   = (float*)wi4;            // r-gate preact  [16][128]
  float* gB   = gA + RB * HID;          // z-gate preact
  float* gC   = gA + 2 * RB * HID;      // n-gate input part (gi_n)
  float* gD   = (float*)wh4;            // n-gate hidden part (gh_n)
  float* in_f = (float*)in4;
  float* h_f  = (float*)h4;

  for (int i = tid; i < NL * RB * 32; i += NTHR)
    h4[i] = make_float4(0.f, 0.f, 0.f, 0.f);

  for (int t = 0; t < T_STEPS; ++t) {
    for (int l = 0; l < NL; ++l) {
      // ---- load layer-0 input rows from x (same threads rewrite in_f later;
      //      visibility to other threads guaranteed by the staging barrier) ----
      if (l == 0) {
        for (int idx = tid; idx < RB * HID; idx += NTHR) {
          const int r = idx >> 7, c = idx & 127;
          in_f[idx] = x[((row_base + r) * T_STEPS + t) * HID + c];
        }
      }

      float Sa[4][4] = {};  // sum Wi[col,:] . in[row,:]
      float Sb[4][4] = {};  // sum Wh[col,:] . h[row,:]
      const float* Wi = w_ih + l * G3 * HID;
      const float* Wh = w_hh + l * G3 * HID;

      for (int kt = 0; kt < NKT; ++kt) {
        __syncthreads();  // prior MAC/update/gate-region reads done before restage
        // ---- stage Wi/Wh k-tile: 3072 float4 each, coalesced, XOR-swizzled ----
        for (int f = tid; f < G3 * 8; f += NTHR) {
          const int j = f >> 3, c = f & 7;
          const int slot = j * 8 + (c ^ ((j >> 2) & 7));
          wi4[slot] = ((const float4*)(Wi + j * HID + kt * KT))[c];
          wh4[slot] = ((const float4*)(Wh + j * HID + kt * KT))[c];
        }
        __syncthreads();
        // ---- MAC over this k-tile ----
#pragma unroll
        for (int c4 = 0; c4 < 8; ++c4) {
          const int k4 = kt * 8 + c4;
          float4 av[4], hv[4], wiv[4], whv[4];
#pragma unroll
          for (int i = 0; i < 4; ++i) {
            av[i] = in4[(4 * rg + i) * 32 + k4];
            hv[i] = h4[(l * RB + 4 * rg + i) * 32 + k4];
          }
#pragma unroll
          for (int j = 0; j < 4; ++j) {
            const int slot = (4 * cg + j) * 8 + (c4 ^ swz);
            wiv[j] = wi4[slot];
            whv[j] = wh4[slot];
          }
#pragma unroll
          for (int i = 0; i < 4; ++i)
#pragma unroll
            for (int j = 0; j < 4; ++j) {
              Sa[i][j] += av[i].x * wiv[j].x + av[i].y * wiv[j].y +
                          av[i].z * wiv[j].z + av[i].w * wiv[j].w;
              Sb[i][j] += hv[i].x * whv[j].x + hv[i].y * whv[j].y +
                          hv[i].z * whv[j].z + hv[i].w * whv[j].w;
            }
        }
      }

      __syncthreads();  // MAC reads of wi4/wh4 done; overlay gates
      // ---- write gate preactivations (+biases) to LDS ----
      {
        const float* bi_p = b_ih + l * G3;
        const float* bh_p = b_hh + l * G3;
#pragma unroll
        for (int j = 0; j < 4; ++j) {
          const int gc = 4 * cg + j;
          const float bi_v = bi_p[gc], bh_v = bh_p[gc];
#pragma unroll
          for (int i = 0; i < 4; ++i) {
            const int row = 4 * rg + i;
            if (gc < 128) {
              gA[row * 128 + gc] = Sa[i][j] + Sb[i][j] + bi_v + bh_v;
            } else if (gc < 256) {
              gB[row * 128 + (gc - 128)] = Sa[i][j] + Sb[i][j] + bi_v + bh_v;
            } else {
              gC[row * 128 + (gc - 256)] = Sa[i][j] + bi_v;
              gD[row * 128 + (gc - 256)] = Sb[i][j] + bh_v;
            }
          }
        }
      }
      __syncthreads();
      // ---- elementwise GRU update + mask ----
      for (int idx = tid; idx < RB * HID; idx += NTHR) {
        const int r = idx >> 7, c = idx & 127;
        const float Av = gA[idx], Bv = gB[idx], Cv = gC[idx], Dv = gD[idx];
        const float rr = sigmoid_f(Av);
        const float zz = sigmoid_f(Bv);
        const float nn = tanh_f(Cv + rr * Dv);
        const float hp = h_f[(l * RB + r) * HID + c];
        const float hn = (1.f - zz) * nn + zz * hp;
        in_f[idx] = hn;  // next layer's input (unmasked), same-thread rewrite
        const int gb = row_base + r;
        const bool msk = invalid[gb * T_STEPS + t] != 0;
        const float hm = msk ? 0.f : hn;
        h_f[(l * RB + r) * HID + c] = hm;  // masked recurrent state
        if (l == NL - 1)
          out[((size_t)gb * T_STEPS + t) * HID + c] = hm;  // masked output
      }
      // next cell's kt=0 barrier orders update writes vs. restage/MAC
    }
  }
}

extern "C" void kernel_launch(void* const* d_in, const int* in_sizes, int n_in,
                              void* d_out, int out_size, void* d_ws, size_t ws_size,
                              hipStream_t stream) {
  const float* x       = (const float*)d_in[0];
  const int*   invalid = (const int*)d_in[1];
  const float* w_ih    = (const float*)d_in[2];
  const float* w_hh    = (const float*)d_in[3];
  const float* b_ih    = (const float*)d_in[4];
  const float* b_hh    = (const float*)d_in[5];
  float* outp = (float*)d_out;
  gru_f32<<<dim3(NBLK), dim3(NTHR), 0, stream>>>(x, invalid, w_ih, w_hh, b_ih, b_hh, outp);
}

// Round 2
// 537.251 us; speedup vs baseline: 40.7991x; 40.7991x over previous
//
#include <hip/hip_runtime.h>

// MultiAgentGRULoop round 2: MFMA, layer-outer, register-resident weights.
//   - 256 blocks x 512 thr (8 waves); block owns 16 batch rows end-to-end.
//   - For each layer: wave w holds B-frags for gate cols w*16+{0,128,256}
//     in VGPRs across all 64 steps (no weight staging in the loop).
//   - d_out doubles as the inter-layer activation buffer (in-place per row;
//     layers 0/1 store UNMASKED h, layer 2 stores masked y, matching ref).
//   - Numeric scheme (fits 256 VGPR): activations split hi/lo bf16,
//     Wh split hi/lo (recurrent path ~f32-exact), Wi hi-only.
//     gi = x_hi*Wi + x_lo*Wi ; gh = h_hi*Wh_hi + h_hi*Wh_lo + h_lo*Wh_hi.
//   - LDS row stride 136 elems (272 B) -> 16B-aligned b128 reads, <=2-way banks.

#define T_STEPS 64
#define HID 128
#define NL 3
#define RB 16
#define NTHR 512
#define NBLK 256
#define LSTR 136

typedef __attribute__((ext_vector_type(8))) short bf16x8;
typedef __attribute__((ext_vector_type(4))) short short4v;
typedef __attribute__((ext_vector_type(4))) float f32x4;

__device__ __forceinline__ unsigned short f2bf(float f) {
  unsigned u = __float_as_uint(f);
  u += 0x7FFFu + ((u >> 16) & 1u);
  return (unsigned short)(u >> 16);
}
__device__ __forceinline__ float bf2f(unsigned short h) {
  return __uint_as_float(((unsigned)h) << 16);
}
__device__ __forceinline__ float sigm(float v) { return 1.f / (1.f + __expf(-v)); }
__device__ __forceinline__ float tanh_f(float v) { return 1.f - 2.f / (__expf(2.f * v) + 1.f); }

__global__ __launch_bounds__(NTHR, 2) void gru_mfma(
    const float* __restrict__ x, const int* __restrict__ invalid,
    const float* __restrict__ w_ih, const float* __restrict__ w_hh,
    const float* __restrict__ b_ih, const float* __restrict__ b_hh,
    float* out)
{
  __shared__ short s_ih[2][RB * LSTR];  // input hi (double-buffered over t)
  __shared__ short s_il[2][RB * LSTR];  // input lo
  __shared__ short s_hh[RB * LSTR];     // h hi
  __shared__ short s_hl[RB * LSTR];     // h lo

  const int tid = threadIdx.x;
  const int wave = tid >> 6, lane = tid & 63;
  const int lr = lane & 15, lq = lane >> 4;
  const int row_base = (int)blockIdx.x * RB;
  const int srow = tid >> 5, scol = (tid & 31) * 4;  // staging map: 4 f32/thread

  for (int l = 0; l < NL; ++l) {
    // ---- one-time per layer: weights -> register B-fragments ----
    bf16x8 wI[3][4], wHhi[3][4], wHlo[3][4];
#pragma unroll
    for (int g = 0; g < 3; ++g)
#pragma unroll
      for (int kf = 0; kf < 4; ++kf) {
        const int wrow = g * HID + wave * 16 + lr;       // B col = lane&15
        const int kofs = kf * 32 + lq * 8;               // same k-map as A
        const float* pI = w_ih + ((size_t)l * 3 * HID + wrow) * HID + kofs;
        const float* pH = w_hh + ((size_t)l * 3 * HID + wrow) * HID + kofs;
        float4 a = *(const float4*)pI, b = *(const float4*)(pI + 4);
        float vi[8] = {a.x, a.y, a.z, a.w, b.x, b.y, b.z, b.w};
#pragma unroll
        for (int j = 0; j < 8; ++j) wI[g][kf][j] = (short)f2bf(vi[j]);
        float4 c = *(const float4*)pH, d = *(const float4*)(pH + 4);
        float vh[8] = {c.x, c.y, c.z, c.w, d.x, d.y, d.z, d.w};
#pragma unroll
        for (int j = 0; j < 8; ++j) {
          unsigned short h = f2bf(vh[j]);
          wHhi[g][kf][j] = (short)h;
          wHlo[g][kf][j] = (short)f2bf(vh[j] - bf2f(h));
        }
      }
    float bI[3], bH[3];
#pragma unroll
    for (int g = 0; g < 3; ++g) {
      bI[g] = b_ih[l * 3 * HID + g * HID + wave * 16 + lr];
      bH[g] = b_hh[l * 3 * HID + g * HID + wave * 16 + lr];
    }

    // ---- h := 0, stage input[t=0] ----
    for (int i = tid; i < RB * LSTR; i += NTHR) { s_hh[i] = 0; s_hl[i] = 0; }
    float hprev[4] = {0.f, 0.f, 0.f, 0.f};
    const float* src = (l == 0) ? x : (const float*)out;
    {
      float4 v = *(const float4*)(src + ((size_t)(row_base + srow) * T_STEPS + 0) * HID + scol);
      float vv[4] = {v.x, v.y, v.z, v.w};
      short4v hi4, lo4;
#pragma unroll
      for (int j = 0; j < 4; ++j) {
        unsigned short h = f2bf(vv[j]);
        hi4[j] = (short)h;
        lo4[j] = (short)f2bf(vv[j] - bf2f(h));
      }
      *(short4v*)&s_ih[0][srow * LSTR + scol] = hi4;
      *(short4v*)&s_il[0][srow * LSTR + scol] = lo4;
    }
    __syncthreads();

    for (int t = 0; t < T_STEPS; ++t) {
      const int buf = t & 1;
      // prefetch next-step input (hidden under MFMA phase)
      float4 pin = make_float4(0.f, 0.f, 0.f, 0.f);
      if (t < T_STEPS - 1)
        pin = *(const float4*)(src + ((size_t)(row_base + srow) * T_STEPS + (t + 1)) * HID + scol);
      int mk[4];
#pragma unroll
      for (int ri = 0; ri < 4; ++ri)
        mk[ri] = invalid[(size_t)(row_base + lq * 4 + ri) * T_STEPS + t];

      f32x4 aI[3], aH[3];
#pragma unroll
      for (int g = 0; g < 3; ++g) {
        aI[g] = (f32x4)(0.f);
        aH[g] = (f32x4)(0.f);
      }
#pragma unroll
      for (int kf = 0; kf < 4; ++kf) {
        const int ao = lr * LSTR + kf * 32 + lq * 8;  // A row = lane&15, k-map = B's
        bf16x8 xh = *(const bf16x8*)&s_ih[buf][ao];
        bf16x8 xl = *(const bf16x8*)&s_il[buf][ao];
        bf16x8 hh = *(const bf16x8*)&s_hh[ao];
        bf16x8 hl = *(const bf16x8*)&s_hl[ao];
#pragma unroll
        for (int g = 0; g < 3; ++g) {
          aI[g] = __builtin_amdgcn_mfma_f32_16x16x32_bf16(xh, wI[g][kf], aI[g], 0, 0, 0);
          aI[g] = __builtin_amdgcn_mfma_f32_16x16x32_bf16(xl, wI[g][kf], aI[g], 0, 0, 0);
          aH[g] = __builtin_amdgcn_mfma_f32_16x16x32_bf16(hh, wHhi[g][kf], aH[g], 0, 0, 0);
          aH[g] = __builtin_amdgcn_mfma_f32_16x16x32_bf16(hh, wHlo[g][kf], aH[g], 0, 0, 0);
          aH[g] = __builtin_amdgcn_mfma_f32_16x16x32_bf16(hl, wHhi[g][kf], aH[g], 0, 0, 0);
        }
      }
      __syncthreads();  // all A-reads of h/in done before overwrite

      // ---- in-register GRU epilogue: lane owns (rows lq*4+ri, col wave*16+lr) ----
#pragma unroll
      for (int ri = 0; ri < 4; ++ri) {
        float rr = sigm(aI[0][ri] + bI[0] + aH[0][ri] + bH[0]);
        float zz = sigm(aI[1][ri] + bI[1] + aH[1][ri] + bH[1]);
        float nn = tanh_f(aI[2][ri] + bI[2] + rr * (aH[2][ri] + bH[2]));
        float hn = (1.f - zz) * nn + zz * hprev[ri];
        float hm = mk[ri] ? 0.f : hn;
        hprev[ri] = hm;
        // inter-layer buffer: UNMASKED h for layers 0/1; masked y for final layer
        out[((size_t)(row_base + lq * 4 + ri) * T_STEPS + t) * HID + wave * 16 + lr] =
            (l == NL - 1) ? hm : hn;
        const int e = (lq * 4 + ri) * LSTR + wave * 16 + lr;
        unsigned short h = f2bf(hm);
        s_hh[e] = (short)h;
        s_hl[e] = (short)f2bf(hm - bf2f(h));
      }
      if (t < T_STEPS - 1) {
        float vv[4] = {pin.x, pin.y, pin.z, pin.w};
        short4v hi4, lo4;
#pragma unroll
        for (int j = 0; j < 4; ++j) {
          unsigned short h = f2bf(vv[j]);
          hi4[j] = (short)h;
          lo4[j] = (short)f2bf(vv[j] - bf2f(h));
        }
        *(short4v*)&s_ih[buf ^ 1][srow * LSTR + scol] = hi4;
        *(short4v*)&s_il[buf ^ 1][srow * LSTR + scol] = lo4;
      }
      __syncthreads();  // h/in[t+1] visible before next cell's A-reads
    }
    __syncthreads();  // layer boundary: d_out writes visible block-wide
  }
}

extern "C" void kernel_launch(void* const* d_in, const int* in_sizes, int n_in,
                              void* d_out, int out_size, void* d_ws, size_t ws_size,
                              hipStream_t stream) {
  const float* x       = (const float*)d_in[0];
  const int*   invalid = (const int*)d_in[1];
  const float* w_ih    = (const float*)d_in[2];
  const float* w_hh    = (const float*)d_in[3];
  const float* b_ih    = (const float*)d_in[4];
  const float* b_hh    = (const float*)d_in[5];
  gru_mfma<<<dim3(NBLK), dim3(NTHR), 0, stream>>>(x, invalid, w_ih, w_hh, b_ih, b_hh,
                                                  (float*)d_out);
}

// Round 3
// 328.064 us; speedup vs baseline: 66.8143x; 1.6376x over previous
//
#include <hip/hip_runtime.h>

// MultiAgentGRULoop round 3: lean bf16 MFMA, f32 register recurrence.
//   - 256 blocks x 512 thr (8 waves); block owns 16 batch rows end-to-end;
//     layer-outer, d_out as inter-layer f32 activation buffer.
//   - Wave w holds bf16 B-frags for gate cols w*16+{0,128,256} in VGPRs for
//     the whole 64-step loop. 24 MFMAs/cell/wave, biases folded into C-init.
//   - h recurrence carried in f32 registers (exact); bf16 only on MFMA paths.
//   - Deferred coalesced out-stores: epilogue -> s_act (LDS f32), stored as
//     dwordx4 at the top of the NEXT cell (latency hidden under MFMA phase).
//   - invalid mask preloaded once to LDS (16 rows x 64 t).

#define T_STEPS 64
#define HID 128
#define NL 3
#define RB 16
#define NTHR 512
#define NBLK 256
#define LSTR 136   // bf16 row stride (shorts): 272 B, 16B-aligned, +4-bank rotation
#define ASTR 132   // f32 act row stride

typedef __attribute__((ext_vector_type(8))) short bf16x8;
typedef __attribute__((ext_vector_type(4))) short short4v;
typedef __attribute__((ext_vector_type(4))) float f32x4;

__device__ __forceinline__ unsigned short f2bf(float f) {
  unsigned u = __float_as_uint(f);
  u += 0x7FFFu + ((u >> 16) & 1u);
  return (unsigned short)(u >> 16);
}
__device__ __forceinline__ float sigm(float v) { return 1.f / (1.f + __expf(-v)); }
__device__ __forceinline__ float tanh_f(float v) { return 1.f - 2.f / (__expf(2.f * v) + 1.f); }

__global__ __launch_bounds__(NTHR, 1) void gru_mfma3(
    const float* __restrict__ x, const int* __restrict__ invalid,
    const float* __restrict__ w_ih, const float* __restrict__ w_hh,
    const float* __restrict__ b_ih, const float* __restrict__ b_hh,
    float* out)
{
  __shared__ short s_in[2][RB * LSTR];  // input bf16, double-buffered over t
  __shared__ short s_h[RB * LSTR];      // h bf16 (masked)
  __shared__ float s_act[RB * ASTR];    // f32 activation out-staging
  __shared__ int   s_msk[RB * T_STEPS]; // invalid mask, whole block-row set

  const int tid = threadIdx.x;
  const int wave = tid >> 6, lane = tid & 63;
  const int lr = lane & 15, lq = lane >> 4;
  const int row_base = (int)blockIdx.x * RB;
  const int srow = tid >> 5, scol = (tid & 31) * 4;  // coalesced f32x4 map

  // ---- invalid mask: contiguous copy, once for all layers ----
  for (int i = tid; i < RB * T_STEPS; i += NTHR)
    s_msk[i] = invalid[(size_t)row_base * T_STEPS + i];

  for (int l = 0; l < NL; ++l) {
    // ---- per layer: weights -> bf16 register B-fragments ----
    bf16x8 wI[3][4], wH[3][4];
#pragma unroll
    for (int g = 0; g < 3; ++g)
#pragma unroll
      for (int kf = 0; kf < 4; ++kf) {
        const int wrow = g * HID + wave * 16 + lr;  // B col = lane&15
        const int kofs = kf * 32 + lq * 8;          // k-map identical to A side
        const float* pI = w_ih + ((size_t)l * 3 * HID + wrow) * HID + kofs;
        const float* pH = w_hh + ((size_t)l * 3 * HID + wrow) * HID + kofs;
        float4 a = *(const float4*)pI, b = *(const float4*)(pI + 4);
        float vi[8] = {a.x, a.y, a.z, a.w, b.x, b.y, b.z, b.w};
        float4 c = *(const float4*)pH, d = *(const float4*)(pH + 4);
        float vh[8] = {c.x, c.y, c.z, c.w, d.x, d.y, d.z, d.w};
#pragma unroll
        for (int j = 0; j < 8; ++j) {
          wI[g][kf][j] = (short)f2bf(vi[j]);
          wH[g][kf][j] = (short)f2bf(vh[j]);
        }
      }
    float bIv[3], bHv[3];
#pragma unroll
    for (int g = 0; g < 3; ++g) {
      bIv[g] = b_ih[l * 3 * HID + g * HID + wave * 16 + lr];
      bHv[g] = b_hh[l * 3 * HID + g * HID + wave * 16 + lr];
    }

    // ---- h := 0, stage input[t=0] ----
    for (int i = tid; i < RB * LSTR; i += NTHR) s_h[i] = 0;
    float hprev[4] = {0.f, 0.f, 0.f, 0.f};
    const float* src = (l == 0) ? x : (const float*)out;
    {
      float4 v = *(const float4*)(src + ((size_t)(row_base + srow) * T_STEPS + 0) * HID + scol);
      short4v hi4 = {(short)f2bf(v.x), (short)f2bf(v.y), (short)f2bf(v.z), (short)f2bf(v.w)};
      *(short4v*)&s_in[0][srow * LSTR + scol] = hi4;
    }
    __syncthreads();

#pragma unroll 2
    for (int t = 0; t < T_STEPS; ++t) {
      const int buf = t & 1;
      // ---- deferred store of previous step's activations (coalesced) ----
      if (t > 0) {
        float4 a = *(const float4*)&s_act[srow * ASTR + scol];
        *(float4*)(out + ((size_t)(row_base + srow) * T_STEPS + (t - 1)) * HID + scol) = a;
      }
      // ---- prefetch next-step input (consumed after barrier1) ----
      float4 pin = make_float4(0.f, 0.f, 0.f, 0.f);
      if (t < T_STEPS - 1)
        pin = *(const float4*)(src + ((size_t)(row_base + srow) * T_STEPS + (t + 1)) * HID + scol);

      // ---- MFMA phase: bias-initialized accumulators ----
      f32x4 aI[3], aH[3];
#pragma unroll
      for (int g = 0; g < 3; ++g) {
        aI[g] = (f32x4)(bIv[g]);
        aH[g] = (f32x4)(bHv[g]);
      }
#pragma unroll
      for (int kf = 0; kf < 4; ++kf) {
        const int ao = lr * LSTR + kf * 32 + lq * 8;  // A row = lane&15
        bf16x8 xh = *(const bf16x8*)&s_in[buf][ao];
        bf16x8 hh = *(const bf16x8*)&s_h[ao];
#pragma unroll
        for (int g = 0; g < 3; ++g) {
          aI[g] = __builtin_amdgcn_mfma_f32_16x16x32_bf16(xh, wI[g][kf], aI[g], 0, 0, 0);
          aH[g] = __builtin_amdgcn_mfma_f32_16x16x32_bf16(hh, wH[g][kf], aH[g], 0, 0, 0);
        }
      }
      __syncthreads();  // A-reads + s_act store-reads done before overwrite

      // ---- epilogue: lane owns (rows lq*4+ri, col wave*16+lr) ----
#pragma unroll
      for (int ri = 0; ri < 4; ++ri) {
        const int row = lq * 4 + ri;
        float rr = sigm(aI[0][ri] + aH[0][ri]);
        float zz = sigm(aI[1][ri] + aH[1][ri]);
        float nn = tanh_f(aI[2][ri] + rr * aH[2][ri]);
        float hn = (1.f - zz) * nn + zz * hprev[ri];
        float hm = s_msk[row * T_STEPS + t] ? 0.f : hn;
        hprev[ri] = hm;
        // layers 0/1 pass UNMASKED h; final layer emits masked y
        s_act[row * ASTR + wave * 16 + lr] = (l == NL - 1) ? hm : hn;
        s_h[row * LSTR + wave * 16 + lr] = (short)f2bf(hm);
      }
      if (t < T_STEPS - 1) {
        short4v hi4 = {(short)f2bf(pin.x), (short)f2bf(pin.y),
                       (short)f2bf(pin.z), (short)f2bf(pin.w)};
        *(short4v*)&s_in[buf ^ 1][srow * LSTR + scol] = hi4;
      }
      __syncthreads();  // epilogue LDS writes visible to next cell
    }
    // ---- flush t=63 activations ----
    {
      float4 a = *(const float4*)&s_act[srow * ASTR + scol];
      *(float4*)(out + ((size_t)(row_base + srow) * T_STEPS + (T_STEPS - 1)) * HID + scol) = a;
    }
    __syncthreads();  // out visible before next layer reads it
  }
}

extern "C" void kernel_launch(void* const* d_in, const int* in_sizes, int n_in,
                              void* d_out, int out_size, void* d_ws, size_t ws_size,
                              hipStream_t stream) {
  const float* x       = (const float*)d_in[0];
  const int*   invalid = (const int*)d_in[1];
  const float* w_ih    = (const float*)d_in[2];
  const float* w_hh    = (const float*)d_in[3];
  const float* b_ih    = (const float*)d_in[4];
  const float* b_hh    = (const float*)d_in[5];
  gru_mfma3<<<dim3(NBLK), dim3(NTHR), 0, stream>>>(x, invalid, w_ih, w_hh, b_ih, b_hh,
                                                   (float*)d_out);
}